// Round 7
// baseline (469.934 us; speedup 1.0000x reference)
//
#include <hip/hip_runtime.h>

// ---------------------------------------------------------------------------
// TT linear layer, all I/O fp32: out[8192,4096] = x @ G^T + bias.
// R10 == R9 resubmit (broker timeout; never ran). gemm_8ph HW-VERIFIED
// (258us, 1066 TF, MfmaUtil 46.6%, 0 bank conflicts) — byte-identical.
// build_g rewritten (R9): 4096 blocks, one per G row (i,j,k). With one k
// per block, thread t=(n,m) needs only its own H row => H stays in
// registers (no Hs LDS, no 2nd sync, no kk loop). ~16 blocks/CU in
// flight (vs 1) hides latency; 8KB contiguous row store. Index mapping
// re-audited vs einsum (r10): row=i*256+j*16+k, col=n*256+m*16+o, all
// operand flattenings verified.
//   d_ws: [0,32MB) G bf16 [4096,4096]; [32MB,96MB) x bf16 [8192,4096].
// ---------------------------------------------------------------------------

typedef short bf16x8 __attribute__((ext_vector_type(8)));
typedef float f32x4 __attribute__((ext_vector_type(4)));

__device__ __forceinline__ unsigned short f2bf_rne(float f) {
  union { float f; unsigned int i; } v;
  v.f = f;
  unsigned int r = v.i + 0x7FFFu + ((v.i >> 16) & 1u);
  return (unsigned short)(r >> 16);
}

__device__ __forceinline__ unsigned int pk2bf_rne(float lo, float hi) {
  return (unsigned int)f2bf_rne(lo) | ((unsigned int)f2bf_rne(hi) << 16);
}

__device__ __forceinline__ unsigned int pk2bf_trunc(float lo, float hi) {
  union { float f; unsigned int u; } a, b;
  a.f = lo; b.f = hi;
  return (b.u & 0xFFFF0000u) | (a.u >> 16);
}

__device__ __forceinline__ void gl2lds16(const void* g, void* l) {
  __builtin_amdgcn_global_load_lds(
      (__attribute__((address_space(1))) void*)g,
      (__attribute__((address_space(3))) void*)l, 16u, 0, 0u);
}

// ---------------------------------------------------------------------------
// x fp32 -> bf16 (RNE), 8 elems/thread.
// ---------------------------------------------------------------------------
__global__ __launch_bounds__(256) void cvt_x(const float* __restrict__ x,
                                             unsigned short* __restrict__ xb) {
  const size_t t = (size_t)blockIdx.x * 256 + threadIdx.x;
  const float4 a0 = *(const float4*)(x + t * 8);
  const float4 a1 = *(const float4*)(x + t * 8 + 4);
  uint4 w = {pk2bf_rne(a0.x, a0.y), pk2bf_rne(a0.z, a0.w),
             pk2bf_rne(a1.x, a1.y), pk2bf_rne(a1.z, a1.w)};
  *(uint4*)(xb + t * 8) = w;
}

// ---------------------------------------------------------------------------
// build_g v3 (R9). One block per G row: bid = i*256 + j*16 + k.
// G[ijk][nmo] = sum_c (sum_b c0[i,n,b] c1[b,j,m,c]) c2[c,k,o].
// Thread t = (n = t>>4, m = t&15) owns output cols [t*16, t*16+16):
//   h[c]  = sum_b c0s[n*16+b] * c1s[b][m*20+c]   (regs, f32x4 x4)
//   o[o_] = sum_c h[c] * c2s[c*16+o_]            (broadcast LDS reads)
// LDS 22KB (c1 padded stride 20 -> 2-way banks, free). Single sync.
// 4096 blocks => ~16 blocks/CU in flight (vs 1 before).
// ---------------------------------------------------------------------------
__global__ __launch_bounds__(256) void build_g(
    const float* __restrict__ core0,   // [1,16,16,16] (i,n,b)
    const float* __restrict__ core1,   // [16,16,16,16] (b,j,m,c)
    const float* __restrict__ core2,   // [16,16,16,1]  (c,k,o)
    unsigned short* __restrict__ G) {  // [4096,4096] bf16
  __shared__ float c0s[256];       // [n*16+b]
  __shared__ float c1s[16 * 320];  // [b][m*20+c] (pad: bank-safe)
  __shared__ float c2s[256];       // [c*16+o], k-slice
  const int t = threadIdx.x;
  const int bid = blockIdx.x;
  const int i = bid >> 8, j = (bid >> 4) & 15, k = bid & 15;

  // ---- stage (coalesced / small) ----
  c0s[t] = core0[i * 256 + t];
  {
    const int m = t >> 4, c = t & 15;
#pragma unroll
    for (int b = 0; b < 16; b++)
      c1s[b * 320 + m * 20 + c] = core1[b * 4096 + j * 256 + t];
  }
  c2s[t] = core2[(t >> 4) * 256 + k * 16 + (t & 15)];
  __syncthreads();

  const int n = t >> 4, m = t & 15;

  // ---- H row (registers): h[c], c = 0..15 ----
  f32x4 h0 = {0.f, 0.f, 0.f, 0.f}, h1 = h0, h2 = h0, h3 = h0;
#pragma unroll
  for (int b = 0; b < 16; b++) {
    const float a = c0s[n * 16 + b];
    const f32x4* p = (const f32x4*)&c1s[b * 320 + m * 20];
    h0 += a * p[0];
    h1 += a * p[1];
    h2 += a * p[2];
    h3 += a * p[3];
  }
  f32x4 h4[4] = {h0, h1, h2, h3};

  // ---- out row slice: o[o_] = sum_c h[c] * c2s[c][o_] ----
  f32x4 o4[4];
  const f32x4 zero = {0.f, 0.f, 0.f, 0.f};
#pragma unroll
  for (int d = 0; d < 4; d++) o4[d] = zero;
#pragma unroll
  for (int c = 0; c < 16; c++) {
    const float hv = h4[c >> 2][c & 3];
    const f32x4* cp = (const f32x4*)&c2s[c * 16];  // broadcast
    o4[0] += hv * cp[0];
    o4[1] += hv * cp[1];
    o4[2] += hv * cp[2];
    o4[3] += hv * cp[3];
  }

  // ---- pack + store 16 bf16 (32B, contiguous 8KB per block) ----
  unsigned int u[8];
#pragma unroll
  for (int d = 0; d < 8; d++)
    u[d] = pk2bf_rne(o4[d >> 1][(d & 1) * 2], o4[d >> 1][(d & 1) * 2 + 1]);
  uint4* gp = (uint4*)&G[(size_t)bid * 4096 + t * 16];
  uint4 s0 = {u[0], u[1], u[2], u[3]};
  uint4 s1 = {u[4], u[5], u[6], u[7]};
  gp[0] = s0;
  gp[1] = s1;
}

// ---------------------------------------------------------------------------
constexpr int Mdim = 8192, Ndim = 4096, Kdim = 4096;

// ---------------------------------------------------------------------------
// 8-phase 256x256 GEMM (m201 template, plain HIP). HW-VERIFIED R8:
// 258us, 1066 TF, MfmaUtil 46.6%, SQ_LDS_BANK_CONFLICT 0. UNCHANGED.
// C[M,N] = A[M,K] * Bt[N,K]^T + bias. A,Bt bf16, fp32 out.
// 512 thr / 8 waves (2Mx4N). LDS: [slot][half][128][64] bf16 per matrix.
// Region-read map (ground truth):
//   sA[s][h]: read at group-phase 1 (rows 0-63, by wm==h waves) AND
//             group-phase 3 (rows 64-127) -> free for restage at phase 4+.
//   sB[s][h]: fully read by end of group-phase 2 -> free at phase 3+.
// Stage placement honors this: B halves at phases 3,4; A halves at 5,6
// (slot0) / next-iter 1,2 (slot1). vmcnt(4) at P4/P8: 12 outstanding,
// drain oldest 8 = exactly the tile read in the following 4 phases.
// Swizzle: phys k-slot p at row r holds logical p^(r&7) (both-sides
// involution, rule 21); banks 2-way (free).
// ---------------------------------------------------------------------------
__global__ __launch_bounds__(512, 2) void gemm_8ph(
    const unsigned short* __restrict__ A,     // [M,K] bf16
    const unsigned short* __restrict__ Bt,    // [N,K] bf16
    const float* __restrict__ bias,           // [N]
    float* __restrict__ C) {                  // [M,N] fp32
  __shared__ __align__(16) unsigned short sA[2][2][8192];  // [slot][half][128*64]
  __shared__ __align__(16) unsigned short sB[2][2][8192];

  const int tid = threadIdx.x, lane = tid & 63, wave = tid >> 6;
  const int wm = wave >> 2, wn = wave & 3;  // 2 x 4 wave grid

  // bijective XCD swizzle: 512 blocks, 64 consecutive per XCD
  const int bid = (int)blockIdx.x;
  const int swz = (bid & 7) * 64 + (bid >> 3);
  const int bm0 = (swz >> 4) * 256, bn0 = (swz & 15) * 256;

  // ---- staging: lane l covers (row = 8*wave + (l>>3), phys slot l&7),
  // source k-slot = (l&7)^(l>>3) so LDS phys slot p holds logical p^(row&7).
  const int srow = 8 * wave + (lane >> 3);
  const int scol = ((lane & 7) ^ (lane >> 3)) * 8;  // elements
  const unsigned short* Ag = A + (size_t)(bm0 + srow) * Kdim + scol;
  const unsigned short* Bg = Bt + (size_t)(bn0 + srow) * Kdim + scol;
  unsigned short* Asl = &sA[0][0][0] + wave * 512 + lane * 8;
  unsigned short* Bsl = &sB[0][0][0] + wave * 512 + lane * 8;

#define STG_A(slot, half, kt)                                                  \
  do {                                                                         \
    gl2lds16(Ag + (size_t)(128 * (half)) * Kdim + (kt) * 64,                   \
             Asl + (slot) * 16384 + (half) * 8192);                            \
    gl2lds16(Ag + (size_t)(128 * (half) + 64) * Kdim + (kt) * 64,              \
             Asl + (slot) * 16384 + (half) * 8192 + 4096);                     \
  } while (0)
#define STG_B(slot, half, kt)                                                  \
  do {                                                                         \
    gl2lds16(Bg + (size_t)(128 * (half)) * Kdim + (kt) * 64,                   \
             Bsl + (slot) * 16384 + (half) * 8192);                            \
    gl2lds16(Bg + (size_t)(128 * (half) + 64) * Kdim + (kt) * 64,              \
             Bsl + (slot) * 16384 + (half) * 8192 + 4096);                     \
  } while (0)

  // ---- fragment reads: row = (group)*16 + (lane&15) -> row&7 == lane&7.
  const int r15 = lane & 15, quad = lane >> 4;
  const int cs0 = ((quad) ^ (lane & 7)) * 8;      // ks=0 phys col (shorts)
  const int cs1 = ((4 + quad) ^ (lane & 7)) * 8;  // ks=1
  const unsigned short* Ard = &sA[0][wm][0] + r15 * 64;
  const unsigned short* Brd = &sB[0][wn >> 1][0] + ((wn & 1) * 64 + r15) * 64;

  bf16x8 afr[4][2];  // current A-quadrant: [m][ks]
  bf16x8 bfr[4][2];  // all 4 N-frags: [nf][ks]
  f32x4 acc[8][4];   // [a*4+m][nf]
  const f32x4 zero = {0.f, 0.f, 0.f, 0.f};
#pragma unroll
  for (int a = 0; a < 8; a++)
#pragma unroll
    for (int b = 0; b < 4; b++) acc[a][b] = zero;

#define LDA(slot, a)                                                           \
  do {                                                                         \
    _Pragma("unroll") for (int m = 0; m < 4; ++m) {                            \
      afr[m][0] = *(const bf16x8*)(Ard + (slot) * 16384 +                      \
                                   ((a) * 64 + m * 16) * 64 + cs0);            \
      afr[m][1] = *(const bf16x8*)(Ard + (slot) * 16384 +                      \
                                   ((a) * 64 + m * 16) * 64 + cs1);            \
    }                                                                          \
  } while (0)
#define LDB2(slot, nlo)                                                        \
  do {                                                                         \
    _Pragma("unroll") for (int n = 0; n < 2; ++n) {                            \
      bfr[(nlo) + n][0] = *(const bf16x8*)(Brd + (slot) * 16384 +              \
                                           ((nlo) + n) * 16 * 64 + cs0);       \
      bfr[(nlo) + n][1] = *(const bf16x8*)(Brd + (slot) * 16384 +              \
                                           ((nlo) + n) * 16 * 64 + cs1);       \
    }                                                                          \
  } while (0)
#define MMQ(a, bh)                                                             \
  do {                                                                         \
    _Pragma("unroll") for (int m = 0; m < 4; ++m)                              \
        _Pragma("unroll") for (int n = 0; n < 2; ++n) {                        \
      acc[(a)*4 + m][(bh)*2 + n] = __builtin_amdgcn_mfma_f32_16x16x32_bf16(    \
          afr[m][0], bfr[(bh)*2 + n][0], acc[(a)*4 + m][(bh)*2 + n], 0, 0, 0); \
      acc[(a)*4 + m][(bh)*2 + n] = __builtin_amdgcn_mfma_f32_16x16x32_bf16(    \
          afr[m][1], bfr[(bh)*2 + n][1], acc[(a)*4 + m][(bh)*2 + n], 0, 0, 0); \
    }                                                                          \
  } while (0)

#define BAR asm volatile("s_barrier" ::: "memory")
#define WLG0 asm volatile("s_waitcnt lgkmcnt(0)" ::: "memory")
#define WLG8 asm volatile("s_waitcnt lgkmcnt(8)" ::: "memory")
#define WVM0 asm volatile("s_waitcnt vmcnt(0)" ::: "memory")
#define WVM4 asm volatile("s_waitcnt vmcnt(4)" ::: "memory")
#define SBAR0 __builtin_amdgcn_sched_barrier(0)
#define PRIO1 __builtin_amdgcn_s_setprio(1)
#define PRIO0 __builtin_amdgcn_s_setprio(0)

  // ---- prologue: tile0 complete into slot0, order-insensitive drain;
  // then tile1's two B halves -> exactly 4 outstanding entering the loop
  // (steady-state invariant; tile1's A halves staged at P1/P2 of iter 0).
  STG_A(0, 0, 0); STG_A(0, 1, 0); STG_B(0, 0, 0); STG_B(0, 1, 0);
  SBAR0;
  WVM0;  // tile0 fully landed, queue empty
  SBAR0;
  STG_B(1, 0, 1); STG_B(1, 1, 1);  // 4 outstanding
  SBAR0;
  BAR;

  // ---- main loop: 2 K-tiles / iter, 8 phases, one STG per phase.
#pragma unroll 1
  for (int i = 0; i < Kdim / 128; ++i) {
    const int t1 = 2 * i + 1;
    const int u0 = (2 * i + 2) & 63;  // wraps harmlessly on last iter
    const int u1 = (2 * i + 3) & 63;
    // P1: read s0 qa=0 + s0.B01; stage s1.A0(t1)
    LDA(0, 0); LDB2(0, 0);
    STG_A(1, 0, t1);
    WLG8; BAR; WLG0; PRIO1; MMQ(0, 0); PRIO0; BAR;
    // P2: read s0.B23; stage s1.A1(t1)
    LDB2(0, 2);
    STG_A(1, 1, t1);
    BAR; WLG0; PRIO1; MMQ(0, 1); PRIO0; BAR;
    // P3: read s0 qa=1 (rows 64-127 of BOTH halves); stage s0.B0(u0)
    LDA(0, 1);
    STG_B(0, 0, u0);
    BAR; WLG0; PRIO1; MMQ(1, 1); PRIO0; BAR;
    // P4: stage s0.B1(u0); vmcnt(4): 12 outstanding -> drain oldest 8 =
    //     t1 {B0,B1,A0,A1} -> slot1 ready for P5.
    STG_B(0, 1, u0);
    BAR; PRIO1; MMQ(1, 0); PRIO0; WVM4; BAR;
    // P5: read s1 qa=0 + s1.B01; stage s0.A0(u0)
    LDA(1, 0); LDB2(1, 0);
    STG_A(0, 0, u0);
    WLG8; BAR; WLG0; PRIO1; MMQ(0, 0); PRIO0; BAR;
    // P6: read s1.B23; stage s0.A1(u0)
    LDB2(1, 2);
    STG_A(0, 1, u0);
    BAR; WLG0; PRIO1; MMQ(0, 1); PRIO0; BAR;
    // P7: read s1 qa=1; stage s1.B0(u1)
    LDA(1, 1);
    STG_B(1, 0, u1);
    BAR; WLG0; PRIO1; MMQ(1, 1); PRIO0; BAR;
    // P8: stage s1.B1(u1); vmcnt(4): drain oldest 8 = u0 {B0,B1,A0,A1}
    //     -> slot0 ready for next iteration's P1.
    STG_B(1, 1, u1);
    BAR; PRIO1; MMQ(1, 0); PRIO0; WVM4; BAR;
  }

  // drain DMA before LDS dealloc / exit
  WVM0;

  // ---- epilogue: C = acc + bias (m97-verified C/D mapping)
#pragma unroll
  for (int nf = 0; nf < 4; ++nf) {
    const int n = bn0 + wn * 64 + nf * 16 + r15;
    const float bv = bias[n];
#pragma unroll
    for (int am = 0; am < 8; ++am) {
      const int mb = bm0 + wm * 128 + am * 16 + quad * 4;
#pragma unroll
      for (int r = 0; r < 4; ++r)
        C[(size_t)(mb + r) * Ndim + n] = acc[am][nf][r] + bv;
    }
  }
#undef STG_A
#undef STG_B
#undef LDA
#undef LDB2
#undef MMQ
#undef BAR
#undef WLG0
#undef WLG8
#undef WVM0
#undef WVM4
#undef SBAR0
#undef PRIO1
#undef PRIO0
}

// ---------------------------------------------------------------------------
// Fallback GEMM (only if ws_size < 96 MB): A fp32 packed in-loop (R1, 500us).
// ---------------------------------------------------------------------------
__global__ __launch_bounds__(256, 3) void gemm_pack(
    const float* __restrict__ A, const unsigned short* __restrict__ Bt,
    const float* __restrict__ bias, float* __restrict__ C) {
  __shared__ __align__(16) unsigned short lA[128 * 32];
  __shared__ __align__(16) unsigned short lB[128 * 32];
  const int tid = threadIdx.x, lane = tid & 63, wave = tid >> 6;
  const int bm0 = blockIdx.y * 128, bn0 = blockIdx.x * 128;
  const int wm = wave >> 1, wn = wave & 1;
  const int srow = lane >> 2, scol = (lane & 3) * 8;
  const unsigned short* Bg = Bt + (size_t)(bn0 + wave * 32 + srow) * Kdim + scol;
  unsigned short* lBp = &lB[wave * 32 * 32 + lane * 8];
  const int arow = wave * 16 + (lane >> 2);
  const int acol = (lane & 3) * 8;
  const float* Ag0 = A + (size_t)(bm0 + arow) * Kdim + acol;
  const float* Ag1 = Ag0 + (size_t)64 * Kdim;
  uint4* lAw0 = (uint4*)&lA[tid * 8];
  uint4* lAw1 = (uint4*)&lA[2048 + tid * 8];

  f32x4 acc[4][4];
  const f32x4 zero = {0.f, 0.f, 0.f, 0.f};
#pragma unroll
  for (int a = 0; a < 4; a++)
#pragma unroll
    for (int b = 0; b < 4; b++) acc[a][b] = zero;
  const int row = lane & 15, quad = lane >> 4;

  for (int k0 = 0; k0 < Kdim; k0 += 32) {
    __syncthreads();
    gl2lds16(Bg + k0, lBp);
    gl2lds16(Bg + k0 + 16 * Kdim, lBp + 16 * 32);
    float4 a0 = *(const float4*)(Ag0 + k0);
    float4 a1 = *(const float4*)(Ag0 + k0 + 4);
    float4 a2 = *(const float4*)(Ag1 + k0);
    float4 a3 = *(const float4*)(Ag1 + k0 + 4);
    uint4 w0 = {pk2bf_trunc(a0.x, a0.y), pk2bf_trunc(a0.z, a0.w),
                pk2bf_trunc(a1.x, a1.y), pk2bf_trunc(a1.z, a1.w)};
    uint4 w1 = {pk2bf_trunc(a2.x, a2.y), pk2bf_trunc(a2.z, a2.w),
                pk2bf_trunc(a3.x, a3.y), pk2bf_trunc(a3.z, a3.w)};
    *lAw0 = w0;
    *lAw1 = w1;
    __syncthreads();

    bf16x8 af[4], bfv[4];
#pragma unroll
    for (int mi = 0; mi < 4; mi++)
      af[mi] = *(const bf16x8*)&lA[(wm * 64 + mi * 16 + row) * 32 + quad * 8];
#pragma unroll
    for (int ni = 0; ni < 4; ni++)
      bfv[ni] = *(const bf16x8*)&lB[(wn * 64 + ni * 16 + row) * 32 + quad * 8];
#pragma unroll
    for (int mi = 0; mi < 4; mi++)
#pragma unroll
      for (int ni = 0; ni < 4; ni++)
        acc[mi][ni] = __builtin_amdgcn_mfma_f32_16x16x32_bf16(
            af[mi], bfv[ni], acc[mi][ni], 0, 0, 0);
  }
#pragma unroll
  for (int ni = 0; ni < 4; ni++) {
    const int n = bn0 + wn * 64 + ni * 16 + row;
    const float bv = bias[n];
#pragma unroll
    for (int mi = 0; mi < 4; mi++) {
      const int mbase = bm0 + wm * 64 + mi * 16 + quad * 4;
#pragma unroll
      for (int r = 0; r < 4; r++)
        C[(size_t)(mbase + r) * Ndim + n] = acc[mi][ni][r] + bv;
    }
  }
}

// ---------------------------------------------------------------------------
extern "C" void kernel_launch(void* const* d_in, const int* in_sizes, int n_in,
                              void* d_out, int out_size, void* d_ws,
                              size_t ws_size, hipStream_t stream) {
  const float* x = (const float*)d_in[0];
  const float* core0 = (const float*)d_in[1];
  const float* core1 = (const float*)d_in[2];
  const float* core2 = (const float*)d_in[3];
  const float* bias = (const float*)d_in[4];
  float* out = (float*)d_out;

  unsigned short* G = (unsigned short*)d_ws;
  const size_t G_BYTES = (size_t)4096 * 4096 * 2;
  const size_t X_BYTES = (size_t)Mdim * Kdim * 2;

  build_g<<<4096, 256, 0, stream>>>(core0, core1, core2, G);

  if (ws_size >= G_BYTES + X_BYTES) {
    unsigned short* Xb = (unsigned short*)((char*)d_ws + G_BYTES);
    cvt_x<<<(Mdim * Kdim) / (256 * 8), 256, 0, stream>>>(x, Xb);
    gemm_8ph<<<(Mdim / 256) * (Ndim / 256), 512, 0, stream>>>(Xb, G, bias, out);
  } else {
    dim3 grid(Ndim / 128, Mdim / 128);
    gemm_pack<<<grid, 256, 0, stream>>>(x, G, bias, out);
  }
}

// Round 12
// 466.177 us; speedup vs baseline: 1.0081x; 1.0081x over previous
//
#include <hip/hip_runtime.h>

// ---------------------------------------------------------------------------
// TT linear layer, all I/O fp32: out[8192,4096] = x @ G^T + bias.
// R15 == R11 resubmit (4th attempt; 3x broker timeout + 1x container
// failure; never ran on HW). R11: (1) fuse cvt_x + build_g into ONE prep
// kernel (saves a launch+gap, overlaps both); (2) drop pre-barrier WLG8
// partial drain in gemm P1/P5 (WLG0 after barrier covers correctness).
// gemm schedule otherwise byte-identical (HW-verified 258us, 1066 TF,
// MfmaUtil 46.6%, 0 bank conflicts). Audits r12-r15: prep branch
// block-uniform; cvt blocks' unused 22.5KB LDS -> ~7 blocks/CU (above
// HBM latency-hiding floor); WLG8 removal preserves read-before-restage;
// fallback path verbatim vs R1/R9-verified kernels.
//   d_ws: [0,32MB) G bf16 [4096,4096]; [32MB,96MB) x bf16 [8192,4096].
// ---------------------------------------------------------------------------

typedef short bf16x8 __attribute__((ext_vector_type(8)));
typedef float f32x4 __attribute__((ext_vector_type(4)));

__device__ __forceinline__ unsigned short f2bf_rne(float f) {
  union { float f; unsigned int i; } v;
  v.f = f;
  unsigned int r = v.i + 0x7FFFu + ((v.i >> 16) & 1u);
  return (unsigned short)(r >> 16);
}

__device__ __forceinline__ unsigned int pk2bf_rne(float lo, float hi) {
  return (unsigned int)f2bf_rne(lo) | ((unsigned int)f2bf_rne(hi) << 16);
}

__device__ __forceinline__ unsigned int pk2bf_trunc(float lo, float hi) {
  union { float f; unsigned int u; } a, b;
  a.f = lo; b.f = hi;
  return (b.u & 0xFFFF0000u) | (a.u >> 16);
}

__device__ __forceinline__ void gl2lds16(const void* g, void* l) {
  __builtin_amdgcn_global_load_lds(
      (__attribute__((address_space(1))) void*)g,
      (__attribute__((address_space(3))) void*)l, 16u, 0, 0u);
}

constexpr int Mdim = 8192, Ndim = 4096, Kdim = 4096;

// ---------------------------------------------------------------------------
// prep: fused cvt_x + build_g. Blocks [0,16384): x fp32->bf16 RNE
// (8 elems/thread, identical to verified cvt_x). Blocks [16384,20480):
// build_g v3 rows (identical to R9-verified build_g, bid' = bid-16384).
// Branch is block-uniform -> no divergent-sync hazard.
// ---------------------------------------------------------------------------
__global__ __launch_bounds__(256) void prep(
    const float* __restrict__ x,       // [8192,4096] fp32
    const float* __restrict__ core0,   // [1,16,16,16] (i,n,b)
    const float* __restrict__ core1,   // [16,16,16,16] (b,j,m,c)
    const float* __restrict__ core2,   // [16,16,16,1]  (c,k,o)
    unsigned short* __restrict__ xb,   // [8192,4096] bf16
    unsigned short* __restrict__ G) {  // [4096,4096] bf16
  __shared__ float c0s[256];       // [n*16+b]
  __shared__ float c1s[16 * 320];  // [b][m*20+c] (pad: bank-safe)
  __shared__ float c2s[256];       // [c*16+o], k-slice
  const int t = threadIdx.x;

  if (blockIdx.x < 16384) {
    // ---- cvt_x path (verified) ----
    const size_t g = (size_t)blockIdx.x * 256 + t;
    const float4 a0 = *(const float4*)(x + g * 8);
    const float4 a1 = *(const float4*)(x + g * 8 + 4);
    uint4 w = {pk2bf_rne(a0.x, a0.y), pk2bf_rne(a0.z, a0.w),
               pk2bf_rne(a1.x, a1.y), pk2bf_rne(a1.z, a1.w)};
    *(uint4*)(xb + g * 8) = w;
    return;
  }

  // ---- build_g path (R9-verified): one block per G row ----
  const int bid = blockIdx.x - 16384;  // i*256 + j*16 + k
  const int i = bid >> 8, j = (bid >> 4) & 15, k = bid & 15;

  c0s[t] = core0[i * 256 + t];
  {
    const int m = t >> 4, c = t & 15;
#pragma unroll
    for (int b = 0; b < 16; b++)
      c1s[b * 320 + m * 20 + c] = core1[b * 4096 + j * 256 + t];
  }
  c2s[t] = core2[(t >> 4) * 256 + k * 16 + (t & 15)];
  __syncthreads();

  const int n = t >> 4, m = t & 15;

  // H row (registers): h[c] = sum_b c0[i,n,b] * c1[b,j,m,c]
  f32x4 h0 = {0.f, 0.f, 0.f, 0.f}, h1 = h0, h2 = h0, h3 = h0;
#pragma unroll
  for (int b = 0; b < 16; b++) {
    const float a = c0s[n * 16 + b];
    const f32x4* p = (const f32x4*)&c1s[b * 320 + m * 20];
    h0 += a * p[0];
    h1 += a * p[1];
    h2 += a * p[2];
    h3 += a * p[3];
  }
  f32x4 h4[4] = {h0, h1, h2, h3};

  // out slice: o[o_] = sum_c h[c] * c2[c,k,o_]
  f32x4 o4[4];
  const f32x4 zero = {0.f, 0.f, 0.f, 0.f};
#pragma unroll
  for (int d = 0; d < 4; d++) o4[d] = zero;
#pragma unroll
  for (int c = 0; c < 16; c++) {
    const float hv = h4[c >> 2][c & 3];
    const f32x4* cp = (const f32x4*)&c2s[c * 16];  // broadcast
    o4[0] += hv * cp[0];
    o4[1] += hv * cp[1];
    o4[2] += hv * cp[2];
    o4[3] += hv * cp[3];
  }

  unsigned int u[8];
#pragma unroll
  for (int d = 0; d < 8; d++)
    u[d] = pk2bf_rne(o4[d >> 1][(d & 1) * 2], o4[d >> 1][(d & 1) * 2 + 1]);
  uint4* gp = (uint4*)&G[(size_t)bid * 4096 + t * 16];
  uint4 s0 = {u[0], u[1], u[2], u[3]};
  uint4 s1 = {u[4], u[5], u[6], u[7]};
  gp[0] = s0;
  gp[1] = s1;
}

// ---------------------------------------------------------------------------
// 8-phase 256x256 GEMM (m201 template, plain HIP). HW-VERIFIED:
// 258us, 1066 TF, MfmaUtil 46.6%, SQ_LDS_BANK_CONFLICT 0.
// R11 delta: WLG8 pre-barrier partial drain removed from P1/P5 (WLG0
// after the barrier enforces all reads; 12 outstanding < lgkmcnt max 15).
// Everything else byte-identical.
// C[M,N] = A[M,K] * Bt[N,K]^T + bias. A,Bt bf16, fp32 out.
// 512 thr / 8 waves (2Mx4N). LDS: [slot][half][128][64] bf16 per matrix.
// Region-read map (ground truth):
//   sA[s][h]: read at group-phase 1 (rows 0-63, by wm==h waves) AND
//             group-phase 3 (rows 64-127) -> free for restage at phase 4+.
//   sB[s][h]: fully read by end of group-phase 2 -> free at phase 3+.
// Stage placement: B halves at phases 3,4; A halves at 5,6 (slot0) /
// next-iter 1,2 (slot1). vmcnt(4) at P4/P8: 12 outstanding per wave,
// drain oldest 8 = exactly the tile read in the following 4 phases.
// Swizzle: phys k-slot p at row r holds logical p^(r&7) (both-sides
// involution, rule 21); banks 2-way (free).
// ---------------------------------------------------------------------------
__global__ __launch_bounds__(512, 2) void gemm_8ph(
    const unsigned short* __restrict__ A,     // [M,K] bf16
    const unsigned short* __restrict__ Bt,    // [N,K] bf16
    const float* __restrict__ bias,           // [N]
    float* __restrict__ C) {                  // [M,N] fp32
  __shared__ __align__(16) unsigned short sA[2][2][8192];  // [slot][half][128*64]
  __shared__ __align__(16) unsigned short sB[2][2][8192];

  const int tid = threadIdx.x, lane = tid & 63, wave = tid >> 6;
  const int wm = wave >> 2, wn = wave & 3;  // 2 x 4 wave grid

  // bijective XCD swizzle: 512 blocks, 64 consecutive per XCD
  const int bid = (int)blockIdx.x;
  const int swz = (bid & 7) * 64 + (bid >> 3);
  const int bm0 = (swz >> 4) * 256, bn0 = (swz & 15) * 256;

  // ---- staging: lane l covers (row = 8*wave + (l>>3), phys slot l&7),
  // source k-slot = (l&7)^(l>>3) so LDS phys slot p holds logical p^(row&7).
  const int srow = 8 * wave + (lane >> 3);
  const int scol = ((lane & 7) ^ (lane >> 3)) * 8;  // elements
  const unsigned short* Ag = A + (size_t)(bm0 + srow) * Kdim + scol;
  const unsigned short* Bg = Bt + (size_t)(bn0 + srow) * Kdim + scol;
  unsigned short* Asl = &sA[0][0][0] + wave * 512 + lane * 8;
  unsigned short* Bsl = &sB[0][0][0] + wave * 512 + lane * 8;

#define STG_A(slot, half, kt)                                                  \
  do {                                                                         \
    gl2lds16(Ag + (size_t)(128 * (half)) * Kdim + (kt) * 64,                   \
             Asl + (slot) * 16384 + (half) * 8192);                            \
    gl2lds16(Ag + (size_t)(128 * (half) + 64) * Kdim + (kt) * 64,              \
             Asl + (slot) * 16384 + (half) * 8192 + 4096);                     \
  } while (0)
#define STG_B(slot, half, kt)                                                  \
  do {                                                                         \
    gl2lds16(Bg + (size_t)(128 * (half)) * Kdim + (kt) * 64,                   \
             Bsl + (slot) * 16384 + (half) * 8192);                            \
    gl2lds16(Bg + (size_t)(128 * (half) + 64) * Kdim + (kt) * 64,              \
             Bsl + (slot) * 16384 + (half) * 8192 + 4096);                     \
  } while (0)

  // ---- fragment reads: row = (group)*16 + (lane&15) -> row&7 == lane&7.
  const int r15 = lane & 15, quad = lane >> 4;
  const int cs0 = ((quad) ^ (lane & 7)) * 8;      // ks=0 phys col (shorts)
  const int cs1 = ((4 + quad) ^ (lane & 7)) * 8;  // ks=1
  const unsigned short* Ard = &sA[0][wm][0] + r15 * 64;
  const unsigned short* Brd = &sB[0][wn >> 1][0] + ((wn & 1) * 64 + r15) * 64;

  bf16x8 afr[4][2];  // current A-quadrant: [m][ks]
  bf16x8 bfr[4][2];  // all 4 N-frags: [nf][ks]
  f32x4 acc[8][4];   // [a*4+m][nf]
  const f32x4 zero = {0.f, 0.f, 0.f, 0.f};
#pragma unroll
  for (int a = 0; a < 8; a++)
#pragma unroll
    for (int b = 0; b < 4; b++) acc[a][b] = zero;

#define LDA(slot, a)                                                           \
  do {                                                                         \
    _Pragma("unroll") for (int m = 0; m < 4; ++m) {                            \
      afr[m][0] = *(const bf16x8*)(Ard + (slot) * 16384 +                      \
                                   ((a) * 64 + m * 16) * 64 + cs0);            \
      afr[m][1] = *(const bf16x8*)(Ard + (slot) * 16384 +                      \
                                   ((a) * 64 + m * 16) * 64 + cs1);            \
    }                                                                          \
  } while (0)
#define LDB2(slot, nlo)                                                        \
  do {                                                                         \
    _Pragma("unroll") for (int n = 0; n < 2; ++n) {                            \
      bfr[(nlo) + n][0] = *(const bf16x8*)(Brd + (slot) * 16384 +              \
                                           ((nlo) + n) * 16 * 64 + cs0);       \
      bfr[(nlo) + n][1] = *(const bf16x8*)(Brd + (slot) * 16384 +              \
                                           ((nlo) + n) * 16 * 64 + cs1);       \
    }                                                                          \
  } while (0)
#define MMQ(a, bh)                                                             \
  do {                                                                         \
    _Pragma("unroll") for (int m = 0; m < 4; ++m)                              \
        _Pragma("unroll") for (int n = 0; n < 2; ++n) {                        \
      acc[(a)*4 + m][(bh)*2 + n] = __builtin_amdgcn_mfma_f32_16x16x32_bf16(    \
          afr[m][0], bfr[(bh)*2 + n][0], acc[(a)*4 + m][(bh)*2 + n], 0, 0, 0); \
      acc[(a)*4 + m][(bh)*2 + n] = __builtin_amdgcn_mfma_f32_16x16x32_bf16(    \
          afr[m][1], bfr[(bh)*2 + n][1], acc[(a)*4 + m][(bh)*2 + n], 0, 0, 0); \
    }                                                                          \
  } while (0)

#define BAR asm volatile("s_barrier" ::: "memory")
#define WLG0 asm volatile("s_waitcnt lgkmcnt(0)" ::: "memory")
#define WVM0 asm volatile("s_waitcnt vmcnt(0)" ::: "memory")
#define WVM4 asm volatile("s_waitcnt vmcnt(4)" ::: "memory")
#define SBAR0 __builtin_amdgcn_sched_barrier(0)
#define PRIO1 __builtin_amdgcn_s_setprio(1)
#define PRIO0 __builtin_amdgcn_s_setprio(0)

  // ---- prologue: tile0 complete into slot0, order-insensitive drain;
  // then tile1's two B halves -> exactly 4 outstanding entering the loop
  // (steady-state invariant; tile1's A halves staged at P1/P2 of iter 0).
  STG_A(0, 0, 0); STG_A(0, 1, 0); STG_B(0, 0, 0); STG_B(0, 1, 0);
  SBAR0;
  WVM0;  // tile0 fully landed, queue empty
  SBAR0;
  STG_B(1, 0, 1); STG_B(1, 1, 1);  // 4 outstanding
  SBAR0;
  BAR;

  // ---- main loop: 2 K-tiles / iter, 8 phases, one STG per phase.
#pragma unroll 1
  for (int i = 0; i < Kdim / 128; ++i) {
    const int t1 = 2 * i + 1;
    const int u0 = (2 * i + 2) & 63;  // wraps harmlessly on last iter
    const int u1 = (2 * i + 3) & 63;
    // P1: read s0 qa=0 + s0.B01; stage s1.A0(t1)
    LDA(0, 0); LDB2(0, 0);
    STG_A(1, 0, t1);
    BAR; WLG0; PRIO1; MMQ(0, 0); PRIO0; BAR;
    // P2: read s0.B23; stage s1.A1(t1)
    LDB2(0, 2);
    STG_A(1, 1, t1);
    BAR; WLG0; PRIO1; MMQ(0, 1); PRIO0; BAR;
    // P3: read s0 qa=1 (rows 64-127 of BOTH halves); stage s0.B0(u0)
    LDA(0, 1);
    STG_B(0, 0, u0);
    BAR; WLG0; PRIO1; MMQ(1, 1); PRIO0; BAR;
    // P4: stage s0.B1(u0); vmcnt(4): 12 outstanding -> drain oldest 8 =
    //     t1 {B0,B1,A0,A1} -> slot1 ready for P5.
    STG_B(0, 1, u0);
    BAR; PRIO1; MMQ(1, 0); PRIO0; WVM4; BAR;
    // P5: read s1 qa=0 + s1.B01; stage s0.A0(u0)
    LDA(1, 0); LDB2(1, 0);
    STG_A(0, 0, u0);
    BAR; WLG0; PRIO1; MMQ(0, 0); PRIO0; BAR;
    // P6: read s1.B23; stage s0.A1(u0)
    LDB2(1, 2);
    STG_A(0, 1, u0);
    BAR; WLG0; PRIO1; MMQ(0, 1); PRIO0; BAR;
    // P7: read s1 qa=1; stage s1.B0(u1)
    LDA(1, 1);
    STG_B(1, 0, u1);
    BAR; WLG0; PRIO1; MMQ(1, 1); PRIO0; BAR;
    // P8: stage s1.B1(u1); vmcnt(4): drain oldest 8 = u0 {B0,B1,A0,A1}
    //     -> slot0 ready for next iteration's P1.
    STG_B(1, 1, u1);
    BAR; PRIO1; MMQ(1, 0); PRIO0; WVM4; BAR;
  }

  // drain DMA before LDS dealloc / exit
  WVM0;

  // ---- epilogue: C = acc + bias (m97-verified C/D mapping)
#pragma unroll
  for (int nf = 0; nf < 4; ++nf) {
    const int n = bn0 + wn * 64 + nf * 16 + r15;
    const float bv = bias[n];
#pragma unroll
    for (int am = 0; am < 8; ++am) {
      const int mb = bm0 + wm * 128 + am * 16 + quad * 4;
#pragma unroll
      for (int r = 0; r < 4; ++r)
        C[(size_t)(mb + r) * Ndim + n] = acc[am][nf][r] + bv;
    }
  }
#undef STG_A
#undef STG_B
#undef LDA
#undef LDB2
#undef MMQ
#undef BAR
#undef WLG0
#undef WVM0
#undef WVM4
#undef SBAR0
#undef PRIO1
#undef PRIO0
}

// ---------------------------------------------------------------------------
// Fallback path kernels (only if ws_size < 96 MB): standalone build_g +
// gemm_pack (A fp32 packed in-loop; R1-verified structure, 500us).
// ---------------------------------------------------------------------------
__global__ __launch_bounds__(256) void build_g_fb(
    const float* __restrict__ core0, const float* __restrict__ core1,
    const float* __restrict__ core2, unsigned short* __restrict__ G) {
  __shared__ float c0s[256];
  __shared__ float c1s[16 * 320];
  __shared__ float c2s[256];
  const int t = threadIdx.x;
  const int bid = blockIdx.x;
  const int i = bid >> 8, j = (bid >> 4) & 15, k = bid & 15;
  c0s[t] = core0[i * 256 + t];
  {
    const int m = t >> 4, c = t & 15;
#pragma unroll
    for (int b = 0; b < 16; b++)
      c1s[b * 320 + m * 20 + c] = core1[b * 4096 + j * 256 + t];
  }
  c2s[t] = core2[(t >> 4) * 256 + k * 16 + (t & 15)];
  __syncthreads();
  const int n = t >> 4, m = t & 15;
  f32x4 h0 = {0.f, 0.f, 0.f, 0.f}, h1 = h0, h2 = h0, h3 = h0;
#pragma unroll
  for (int b = 0; b < 16; b++) {
    const float a = c0s[n * 16 + b];
    const f32x4* p = (const f32x4*)&c1s[b * 320 + m * 20];
    h0 += a * p[0]; h1 += a * p[1]; h2 += a * p[2]; h3 += a * p[3];
  }
  f32x4 h4[4] = {h0, h1, h2, h3};
  f32x4 o4[4];
  const f32x4 zero = {0.f, 0.f, 0.f, 0.f};
#pragma unroll
  for (int d = 0; d < 4; d++) o4[d] = zero;
#pragma unroll
  for (int c = 0; c < 16; c++) {
    const float hv = h4[c >> 2][c & 3];
    const f32x4* cp = (const f32x4*)&c2s[c * 16];
    o4[0] += hv * cp[0]; o4[1] += hv * cp[1];
    o4[2] += hv * cp[2]; o4[3] += hv * cp[3];
  }
  unsigned int u[8];
#pragma unroll
  for (int d = 0; d < 8; d++)
    u[d] = pk2bf_rne(o4[d >> 1][(d & 1) * 2], o4[d >> 1][(d & 1) * 2 + 1]);
  uint4* gp = (uint4*)&G[(size_t)bid * 4096 + t * 16];
  uint4 s0 = {u[0], u[1], u[2], u[3]};
  uint4 s1 = {u[4], u[5], u[6], u[7]};
  gp[0] = s0;
  gp[1] = s1;
}

__global__ __launch_bounds__(256, 3) void gemm_pack(
    const float* __restrict__ A, const unsigned short* __restrict__ Bt,
    const float* __restrict__ bias, float* __restrict__ C) {
  __shared__ __align__(16) unsigned short lA[128 * 32];
  __shared__ __align__(16) unsigned short lB[128 * 32];
  const int tid = threadIdx.x, lane = tid & 63, wave = tid >> 6;
  const int bm0 = blockIdx.y * 128, bn0 = blockIdx.x * 128;
  const int wm = wave >> 1, wn = wave & 1;
  const int srow = lane >> 2, scol = (lane & 3) * 8;
  const unsigned short* Bg = Bt + (size_t)(bn0 + wave * 32 + srow) * Kdim + scol;
  unsigned short* lBp = &lB[wave * 32 * 32 + lane * 8];
  const int arow = wave * 16 + (lane >> 2);
  const int acol = (lane & 3) * 8;
  const float* Ag0 = A + (size_t)(bm0 + arow) * Kdim + acol;
  const float* Ag1 = Ag0 + (size_t)64 * Kdim;
  uint4* lAw0 = (uint4*)&lA[tid * 8];
  uint4* lAw1 = (uint4*)&lA[2048 + tid * 8];

  f32x4 acc[4][4];
  const f32x4 zero = {0.f, 0.f, 0.f, 0.f};
#pragma unroll
  for (int a = 0; a < 4; a++)
#pragma unroll
    for (int b = 0; b < 4; b++) acc[a][b] = zero;
  const int row = lane & 15, quad = lane >> 4;

  for (int k0 = 0; k0 < Kdim; k0 += 32) {
    __syncthreads();
    gl2lds16(Bg + k0, lBp);
    gl2lds16(Bg + k0 + 16 * Kdim, lBp + 16 * 32);
    float4 a0 = *(const float4*)(Ag0 + k0);
    float4 a1 = *(const float4*)(Ag0 + k0 + 4);
    float4 a2 = *(const float4*)(Ag1 + k0);
    float4 a3 = *(const float4*)(Ag1 + k0 + 4);
    uint4 w0 = {pk2bf_trunc(a0.x, a0.y), pk2bf_trunc(a0.z, a0.w),
                pk2bf_trunc(a1.x, a1.y), pk2bf_trunc(a1.z, a1.w)};
    uint4 w1 = {pk2bf_trunc(a2.x, a2.y), pk2bf_trunc(a2.z, a2.w),
                pk2bf_trunc(a3.x, a3.y), pk2bf_trunc(a3.z, a3.w)};
    *lAw0 = w0;
    *lAw1 = w1;
    __syncthreads();

    bf16x8 af[4], bfv[4];
#pragma unroll
    for (int mi = 0; mi < 4; mi++)
      af[mi] = *(const bf16x8*)&lA[(wm * 64 + mi * 16 + row) * 32 + quad * 8];
#pragma unroll
    for (int ni = 0; ni < 4; ni++)
      bfv[ni] = *(const bf16x8*)&lB[(wn * 64 + ni * 16 + row) * 32 + quad * 8];
#pragma unroll
    for (int mi = 0; mi < 4; mi++)
#pragma unroll
      for (int ni = 0; ni < 4; ni++)
        acc[mi][ni] = __builtin_amdgcn_mfma_f32_16x16x32_bf16(
            af[mi], bfv[ni], acc[mi][ni], 0, 0, 0);
  }
#pragma unroll
  for (int ni = 0; ni < 4; ni++) {
    const int n = bn0 + wn * 64 + ni * 16 + row;
    const float bv = bias[n];
#pragma unroll
    for (int mi = 0; mi < 4; mi++) {
      const int mbase = bm0 + wm * 64 + mi * 16 + quad * 4;
#pragma unroll
      for (int r = 0; r < 4; r++)
        C[(size_t)(mbase + r) * Ndim + n] = acc[mi][ni][r] + bv;
    }
  }
}

// ---------------------------------------------------------------------------
extern "C" void kernel_launch(void* const* d_in, const int* in_sizes, int n_in,
                              void* d_out, int out_size, void* d_ws,
                              size_t ws_size, hipStream_t stream) {
  const float* x = (const float*)d_in[0];
  const float* core0 = (const float*)d_in[1];
  const float* core1 = (const float*)d_in[2];
  const float* core2 = (const float*)d_in[3];
  const float* bias = (const float*)d_in[4];
  float* out = (float*)d_out;

  unsigned short* G = (unsigned short*)d_ws;
  const size_t G_BYTES = (size_t)4096 * 4096 * 2;
  const size_t X_BYTES = (size_t)Mdim * Kdim * 2;

  if (ws_size >= G_BYTES + X_BYTES) {
    unsigned short* Xb = (unsigned short*)((char*)d_ws + G_BYTES);
    prep<<<16384 + 4096, 256, 0, stream>>>(x, core0, core1, core2, Xb, G);
    gemm_8ph<<<(Mdim / 256) * (Ndim / 256), 512, 0, stream>>>(Xb, G, bias, out);
  } else {
    build_g_fb<<<4096, 256, 0, stream>>>(core0, core1, core2, G);
    dim3 grid(Ndim / 128, Mdim / 128);
    gemm_pack<<<grid, 256, 0, stream>>>(x, G, bias, out);
  }
}